// Round 4
// baseline (203.303 us; speedup 1.0000x reference)
//
#include <hip/hip_runtime.h>

#define N_NODES 100000
#define N_EDGES 300000

// ---------------------------------------------------------------------------
// Zero both aggregation buffers in one launch.
// ---------------------------------------------------------------------------
__global__ __launch_bounds__(256) void zero_ws_kernel(float4* __restrict__ p,
                                                      int n4)
{
    int stride = gridDim.x * 256;
    for (int i = blockIdx.x * 256 + threadIdx.x; i < n4; i += stride)
        p[i] = make_float4(0.f, 0.f, 0.f, 0.f);
}

// Broadcast lane (i) of the lane's own 32-half from a wave64 register.
__device__ __forceinline__ float half_bcast(int hbits, int i, int hihalf)
{
    float ha = __int_as_float(__builtin_amdgcn_readlane(hbits, i));
    float hb = __int_as_float(__builtin_amdgcn_readlane(hbits, i + 32));
    return hihalf ? hb : ha;
}

// ---------------------------------------------------------------------------
// Layer 1 edge kernel: 16 lanes per edge, lane owns channels {2c, 2c+1}.
// ---------------------------------------------------------------------------
__global__ __launch_bounds__(256) void edge1_kernel(
    const float* __restrict__ x, const int* __restrict__ src,
    const int* __restrict__ dst, const float* __restrict__ ea,
    const float* __restrict__ nn1_w, const float* __restrict__ nn1_b,
    float* __restrict__ agg)
{
    int gid = blockIdx.x * 256 + threadIdx.x;
    int e = gid >> 4;
    int c = gid & 15;
    if (e >= N_EDGES) return;
    int s = src[e], d = dst[e];
    float2 a = ((const float2*)ea)[e];
    float2 xv = ((const float2*)x)[s];
    int o0 = 2 * c, o1 = 2 * c + 1;
    float2 w0a = ((const float2*)nn1_w)[o0];
    float2 w0b = ((const float2*)nn1_w)[o1];
    float2 w1a = ((const float2*)nn1_w)[32 + o0];
    float2 w1b = ((const float2*)nn1_w)[32 + o1];
    float2 b0 = ((const float2*)nn1_b)[c];
    float2 b1 = ((const float2*)nn1_b)[16 + c];
    float m0 = xv.x * fmaf(a.x, w0a.x, fmaf(a.y, w0a.y, b0.x))
             + xv.y * fmaf(a.x, w1a.x, fmaf(a.y, w1a.y, b1.x));
    float m1 = xv.x * fmaf(a.x, w0b.x, fmaf(a.y, w0b.y, b0.y))
             + xv.y * fmaf(a.x, w1b.x, fmaf(a.y, w1b.y, b1.y));
    atomicAdd(&agg[d * 32 + o0], m0);
    atomicAdd(&agg[d * 32 + o1], m1);
}

// ---------------------------------------------------------------------------
// Node kernel 1 (register-weight rewrite):
//   h1 = relu(agg1 + x@root1 + bias1)
//   P = h1@A, Q = h1@B, R = h1@C, pre2 = h1@root2 + bias2
// Weight columns live in 128 VGPRs/lane; h broadcast via v_readlane.
// Wave64 = 2 nodes; grid-stride over node pairs. No LDS in the hot loop.
// ---------------------------------------------------------------------------
__global__ __launch_bounds__(256) void node1_kernel(
    const float* __restrict__ x, const float* __restrict__ agg,
    const float* __restrict__ root1, const float* __restrict__ bias1,
    const float* __restrict__ nn2_w, const float* __restrict__ nn2_b,
    const float* __restrict__ root2, const float* __restrict__ bias2,
    float* __restrict__ pre2, float* __restrict__ P,
    float* __restrict__ Q, float* __restrict__ R)
{
    __shared__ float Ws[4][32 * 33];   // padded: column reads conflict-free
    int t = threadIdx.x;
    for (int k = t; k < 1024; k += 256) {
        int i = k >> 5, oo = k & 31;
        float2 w = ((const float2*)nn2_w)[k];
        Ws[0][i * 33 + oo] = w.x;        // A[i][o]
        Ws[1][i * 33 + oo] = w.y;        // B[i][o]
        Ws[2][i * 33 + oo] = nn2_b[k];   // C[i][o]
        Ws[3][i * 33 + oo] = root2[k];   // root2[i][o]
    }
    __syncthreads();

    int lane = t & 63;
    int o = lane & 31;
    int hihalf = lane >> 5;
    float wa[32], wb[32], wc[32], wr[32];
    #pragma unroll
    for (int i = 0; i < 32; ++i) {
        wa[i] = Ws[0][i * 33 + o];
        wb[i] = Ws[1][i * 33 + o];
        wc[i] = Ws[2][i * 33 + o];
        wr[i] = Ws[3][i * 33 + o];
    }
    float r1a = root1[o], r1b = root1[32 + o];
    float b1 = bias1[o], b2 = bias2[o];

    int gw = blockIdx.x * 4 + (t >> 6);
    int nw = gridDim.x * 4;
    for (int pair = gw; pair < N_NODES / 2; pair += nw) {
        int n = pair * 2 + hihalf;
        float2 xv = ((const float2*)x)[n];
        float h = agg[n * 32 + o] + fmaf(xv.x, r1a, fmaf(xv.y, r1b, b1));
        h = fmaxf(h, 0.f);
        int hbits = __float_as_int(h);
        float p = 0.f, q = 0.f, r = 0.f, t2 = b2;
        #pragma unroll
        for (int i = 0; i < 32; ++i) {
            float hi = half_bcast(hbits, i, hihalf);
            p  = fmaf(hi, wa[i], p);
            q  = fmaf(hi, wb[i], q);
            r  = fmaf(hi, wc[i], r);
            t2 = fmaf(hi, wr[i], t2);
        }
        P[n * 32 + o] = p;
        Q[n * 32 + o] = q;
        R[n * 32 + o] = r;
        pre2[n * 32 + o] = t2;
    }
}

// ---------------------------------------------------------------------------
// Layer 2 edge kernel: 16 lanes/edge, float2 gathers of P/Q/R.
// ---------------------------------------------------------------------------
__global__ __launch_bounds__(256) void edge2_kernel(
    const int* __restrict__ src, const int* __restrict__ dst,
    const float* __restrict__ ea,
    const float* __restrict__ P, const float* __restrict__ Q,
    const float* __restrict__ R, float* __restrict__ agg)
{
    int gid = blockIdx.x * 256 + threadIdx.x;
    int e = gid >> 4;
    int c = gid & 15;
    if (e >= N_EDGES) return;
    int s = src[e], d = dst[e];
    float2 a = ((const float2*)ea)[e];
    float2 pv = ((const float2*)P)[s * 16 + c];
    float2 qv = ((const float2*)Q)[s * 16 + c];
    float2 rv = ((const float2*)R)[s * 16 + c];
    float m0 = fmaf(a.x, pv.x, fmaf(a.y, qv.x, rv.x));
    float m1 = fmaf(a.x, pv.y, fmaf(a.y, qv.y, rv.y));
    atomicAdd(&agg[d * 32 + 2 * c], m0);
    atomicAdd(&agg[d * 32 + 2 * c + 1], m1);
}

// ---------------------------------------------------------------------------
// Node kernel 2 (epilogue, register-weight rewrite):
//   h2 = relu(agg2 + pre2); z = relu(h2@fc1_w.T + fc1_b);
//   out = z@fc2_w.T + fc2_b
// ---------------------------------------------------------------------------
__global__ __launch_bounds__(256) void node2_kernel(
    const float* __restrict__ agg, const float* __restrict__ pre2,
    const float* __restrict__ fc1_w, const float* __restrict__ fc1_b,
    const float* __restrict__ fc2_w, const float* __restrict__ fc2_b,
    float* __restrict__ out)
{
    int t = threadIdx.x;
    int lane = t & 63;
    int o = lane & 31;
    int hihalf = lane >> 5;
    float wf[32];
    #pragma unroll
    for (int i = 0; i < 32; ++i) wf[i] = fc1_w[o * 32 + i];
    float zb = fc1_b[o];
    float w2 = fc2_w[o];
    float ob = fc2_b[0];

    int gw = blockIdx.x * 4 + (t >> 6);
    int nw = gridDim.x * 4;
    for (int pair = gw; pair < N_NODES / 2; pair += nw) {
        int n = pair * 2 + hihalf;
        float h = agg[n * 32 + o] + pre2[n * 32 + o];
        h = fmaxf(h, 0.f);
        int hbits = __float_as_int(h);
        float z = zb;
        #pragma unroll
        for (int i = 0; i < 32; ++i)
            z = fmaf(half_bcast(hbits, i, hihalf), wf[i], z);
        z = fmaxf(z, 0.f) * w2;
        #pragma unroll
        for (int off = 16; off; off >>= 1)
            z += __shfl_down(z, off, 32);
        if (o == 0) out[n] = z + ob;
    }
}

extern "C" void kernel_launch(void* const* d_in, const int* in_sizes, int n_in,
                              void* d_out, int out_size, void* d_ws, size_t ws_size,
                              hipStream_t stream) {
    const float* x      = (const float*)d_in[0];
    const int*   ei     = (const int*)d_in[1];
    const float* ea     = (const float*)d_in[2];
    const float* nn1_w  = (const float*)d_in[3];
    const float* nn1_b  = (const float*)d_in[4];
    const float* root1  = (const float*)d_in[5];
    const float* bias1  = (const float*)d_in[6];
    const float* nn2_w  = (const float*)d_in[7];
    const float* nn2_b  = (const float*)d_in[8];
    const float* root2  = (const float*)d_in[9];
    const float* bias2  = (const float*)d_in[10];
    const float* fc1_w  = (const float*)d_in[11];
    const float* fc1_b  = (const float*)d_in[12];
    const float* fc2_w  = (const float*)d_in[13];
    const float* fc2_b  = (const float*)d_in[14];
    float* out = (float*)d_out;

    float* ws   = (float*)d_ws;
    float* agg1 = ws;                         // N*32
    float* agg2 = ws + (size_t)N_NODES * 32;  // N*32
    float* pre2 = ws + (size_t)N_NODES * 64;  // N*32
    float* P    = ws + (size_t)N_NODES * 96;  // N*32
    float* Q    = ws + (size_t)N_NODES * 128; // N*32
    float* R    = ws + (size_t)N_NODES * 160; // N*32

    const int* src = ei;
    const int* dst = ei + N_EDGES;

    int n4 = (N_NODES * 64) / 4;
    zero_ws_kernel<<<2048, 256, 0, stream>>>((float4*)agg1, n4);

    edge1_kernel<<<(N_EDGES * 16) / 256, 256, 0, stream>>>(
        x, src, dst, ea, nn1_w, nn1_b, agg1);
    node1_kernel<<<512, 256, 0, stream>>>(
        x, agg1, root1, bias1, nn2_w, nn2_b, root2, bias2, pre2, P, Q, R);
    edge2_kernel<<<(N_EDGES * 16) / 256, 256, 0, stream>>>(
        src, dst, ea, P, Q, R, agg2);
    node2_kernel<<<512, 256, 0, stream>>>(
        agg2, pre2, fc1_w, fc1_b, fc2_w, fc2_b, out);
}

// Round 5
// 133.300 us; speedup vs baseline: 1.5252x; 1.5252x over previous
//
#include <hip/hip_runtime.h>

#define N_NODES 100000
#define N_EDGES 300000
#define CAP 32

// Broadcast element i of the lane's own 32-half from a wave64 register.
__device__ __forceinline__ float half_bcast(int hbits, int i, int hihalf)
{
    float ha = __int_as_float(__builtin_amdgcn_readlane(hbits, i));
    float hb = __int_as_float(__builtin_amdgcn_readlane(hbits, i + 32));
    return hihalf ? hb : ha;
}

// ---------------------------------------------------------------------------
// K1: zero the per-node edge counters (0.4 MB).
// ---------------------------------------------------------------------------
__global__ __launch_bounds__(256) void zero_cnt_kernel(int4* __restrict__ p,
                                                       int n4)
{
    int stride = gridDim.x * 256;
    for (int i = blockIdx.x * 256 + threadIdx.x; i < n4; i += stride)
        p[i] = make_int4(0, 0, 0, 0);
}

// ---------------------------------------------------------------------------
// K2: bucket scatter. One thread per edge; int atomic gives the slot index.
// slot = { as_float(src), a0, a1, unused } -> single 16B write.
// ---------------------------------------------------------------------------
__global__ __launch_bounds__(256) void scatter_kernel(
    const int* __restrict__ src, const int* __restrict__ dst,
    const float* __restrict__ ea,
    int* __restrict__ cnt, float4* __restrict__ slots)
{
    int e = blockIdx.x * 256 + threadIdx.x;
    if (e >= N_EDGES) return;
    int s = src[e], d = dst[e];
    float2 a = ((const float2*)ea)[e];
    int pos = atomicAdd(&cnt[d], 1);
    if (pos < CAP)
        slots[d * CAP + pos] = make_float4(__int_as_float(s), a.x, a.y, 0.f);
}

// ---------------------------------------------------------------------------
// K3: fused layer-1 gather-aggregate + node1 compute.
// Per 32-lane half: one dst node; lane = channel o.
//   agg1[o] = sum_j  x0*(a0*w00+a1*w01+b0) + x1*(a0*w10+a1*w11+b1)
//   h1 = relu(agg1 + x@root1 + bias1)
//   P = h1@A, Q = h1@B, R = h1@C, pre2 = h1@root2 + bias2
// Weight columns in 128 VGPRs; h1 broadcast via v_readlane (no LDS in loop).
// ---------------------------------------------------------------------------
__global__ __launch_bounds__(256) void layer1_kernel(
    const float* __restrict__ x, const int* __restrict__ cnt,
    const float4* __restrict__ slots,
    const float* __restrict__ nn1_w, const float* __restrict__ nn1_b,
    const float* __restrict__ root1, const float* __restrict__ bias1,
    const float* __restrict__ nn2_w, const float* __restrict__ nn2_b,
    const float* __restrict__ root2, const float* __restrict__ bias2,
    float* __restrict__ P, float* __restrict__ Q,
    float* __restrict__ R, float* __restrict__ pre2)
{
    __shared__ float Ws[4][32 * 33];
    int t = threadIdx.x;
    for (int k = t; k < 1024; k += 256) {
        int i = k >> 5, oo = k & 31;
        float2 w = ((const float2*)nn2_w)[k];
        Ws[0][i * 33 + oo] = w.x;        // A[i][o]
        Ws[1][i * 33 + oo] = w.y;        // B[i][o]
        Ws[2][i * 33 + oo] = nn2_b[k];   // C[i][o]
        Ws[3][i * 33 + oo] = root2[k];   // root2[i][o]
    }
    __syncthreads();

    int lane = t & 63, o = lane & 31, hihalf = lane >> 5;
    float wa[32], wb[32], wc[32], wr[32];
    #pragma unroll
    for (int i = 0; i < 32; ++i) {
        wa[i] = Ws[0][i * 33 + o];
        wb[i] = Ws[1][i * 33 + o];
        wc[i] = Ws[2][i * 33 + o];
        wr[i] = Ws[3][i * 33 + o];
    }
    float2 w0 = ((const float2*)nn1_w)[o];        // nn1_w rows o, 32+o
    float2 w1 = ((const float2*)nn1_w)[32 + o];
    float b0 = nn1_b[o], b1v = nn1_b[32 + o];
    float r1a = root1[o], r1b = root1[32 + o];
    float bi1 = bias1[o], b2 = bias2[o];

    int gw = blockIdx.x * 4 + (t >> 6);
    int nw = gridDim.x * 4;
    for (int pair = gw; pair < N_NODES / 2; pair += nw) {
        int n = pair * 2 + hihalf;
        int c = min(cnt[n], CAP);
        float acc = 0.f;
        for (int j = 0; j < c; ++j) {
            float4 sl = slots[n * CAP + j];
            int s = __float_as_int(sl.x);
            float2 xv = ((const float2*)x)[s];
            acc += xv.x * fmaf(sl.y, w0.x, fmaf(sl.z, w0.y, b0))
                 + xv.y * fmaf(sl.y, w1.x, fmaf(sl.z, w1.y, b1v));
        }
        float2 xn = ((const float2*)x)[n];
        float h = acc + fmaf(xn.x, r1a, fmaf(xn.y, r1b, bi1));
        h = fmaxf(h, 0.f);
        int hbits = __float_as_int(h);
        float p = 0.f, q = 0.f, r = 0.f, t2 = b2;
        #pragma unroll
        for (int i = 0; i < 32; ++i) {
            float hi = half_bcast(hbits, i, hihalf);
            p  = fmaf(hi, wa[i], p);
            q  = fmaf(hi, wb[i], q);
            r  = fmaf(hi, wc[i], r);
            t2 = fmaf(hi, wr[i], t2);
        }
        P[n * 32 + o] = p;
        Q[n * 32 + o] = q;
        R[n * 32 + o] = r;
        pre2[n * 32 + o] = t2;
    }
}

// ---------------------------------------------------------------------------
// K4: fused layer-2 gather-aggregate + epilogue.
//   agg2[o] = sum_j a0*P[s][o] + a1*Q[s][o] + R[s][o]   (coalesced 128B rows)
//   h2 = relu(agg2 + pre2); z = relu(h2@fc1_w.T + fc1_b)
//   out = z@fc2_w.T + fc2_b
// ---------------------------------------------------------------------------
__global__ __launch_bounds__(256) void layer2_kernel(
    const int* __restrict__ cnt, const float4* __restrict__ slots,
    const float* __restrict__ P, const float* __restrict__ Q,
    const float* __restrict__ R, const float* __restrict__ pre2,
    const float* __restrict__ fc1_w, const float* __restrict__ fc1_b,
    const float* __restrict__ fc2_w, const float* __restrict__ fc2_b,
    float* __restrict__ out)
{
    int t = threadIdx.x, lane = t & 63, o = lane & 31, hihalf = lane >> 5;
    float wf[32];
    #pragma unroll
    for (int i = 0; i < 32; ++i) wf[i] = fc1_w[o * 32 + i];
    float zb = fc1_b[o], w2 = fc2_w[o], ob = fc2_b[0];

    int gw = blockIdx.x * 4 + (t >> 6);
    int nw = gridDim.x * 4;
    for (int pair = gw; pair < N_NODES / 2; pair += nw) {
        int n = pair * 2 + hihalf;
        int c = min(cnt[n], CAP);
        float acc = 0.f;
        for (int j = 0; j < c; ++j) {
            float4 sl = slots[n * CAP + j];
            int s = __float_as_int(sl.x);
            acc += fmaf(sl.y, P[s * 32 + o],
                   fmaf(sl.z, Q[s * 32 + o], R[s * 32 + o]));
        }
        float h = fmaxf(acc + pre2[n * 32 + o], 0.f);
        int hbits = __float_as_int(h);
        float z = zb;
        #pragma unroll
        for (int i = 0; i < 32; ++i)
            z = fmaf(half_bcast(hbits, i, hihalf), wf[i], z);
        z = fmaxf(z, 0.f) * w2;
        #pragma unroll
        for (int off = 16; off; off >>= 1)
            z += __shfl_down(z, off, 32);
        if (o == 0) out[n] = z + ob;
    }
}

extern "C" void kernel_launch(void* const* d_in, const int* in_sizes, int n_in,
                              void* d_out, int out_size, void* d_ws, size_t ws_size,
                              hipStream_t stream) {
    const float* x      = (const float*)d_in[0];
    const int*   ei     = (const int*)d_in[1];
    const float* ea     = (const float*)d_in[2];
    const float* nn1_w  = (const float*)d_in[3];
    const float* nn1_b  = (const float*)d_in[4];
    const float* root1  = (const float*)d_in[5];
    const float* bias1  = (const float*)d_in[6];
    const float* nn2_w  = (const float*)d_in[7];
    const float* nn2_b  = (const float*)d_in[8];
    const float* root2  = (const float*)d_in[9];
    const float* bias2  = (const float*)d_in[10];
    const float* fc1_w  = (const float*)d_in[11];
    const float* fc1_b  = (const float*)d_in[12];
    const float* fc2_w  = (const float*)d_in[13];
    const float* fc2_b  = (const float*)d_in[14];
    float* out = (float*)d_out;

    float* ws = (float*)d_ws;
    // layout in float units:
    //   cnt   @ 0          (100k ints)
    //   slots @ 262144     (100k * CAP * 4 floats = 12.8M floats, 16B aligned)
    //   P/Q/R/pre2 after
    int*    cnt   = (int*)ws;
    float4* slots = (float4*)(ws + 262144);
    float*  P     = ws + 262144 + 12800000;
    float*  Q     = P + (size_t)N_NODES * 32;
    float*  R     = Q + (size_t)N_NODES * 32;
    float*  pre2  = R + (size_t)N_NODES * 32;

    const int* src = ei;
    const int* dst = ei + N_EDGES;

    zero_cnt_kernel<<<256, 256, 0, stream>>>((int4*)cnt, N_NODES / 4);
    scatter_kernel<<<(N_EDGES + 255) / 256, 256, 0, stream>>>(
        src, dst, ea, cnt, slots);
    layer1_kernel<<<2048, 256, 0, stream>>>(
        x, cnt, slots, nn1_w, nn1_b, root1, bias1,
        nn2_w, nn2_b, root2, bias2, P, Q, R, pre2);
    layer2_kernel<<<2048, 256, 0, stream>>>(
        cnt, slots, P, Q, R, pre2, fc1_w, fc1_b, fc2_w, fc2_b, out);
}